// Round 1
// baseline (2136.571 us; speedup 1.0000x reference)
//
#include <hip/hip_runtime.h>

// LSTM fused persistent kernel.
// B=256, T=1024, I=64, H=25 (4H=100 gates), O=64. fp32 in/out.
// One block per batch element (256 blocks, 1 per CU), 128 threads.
// Gate weights live in per-thread registers; x double-buffered in LDS;
// c lives in registers of threads 0..24; out GEMM fused (W_fc in LDS).

#define Bn 256
#define Tn 1024
#define In 64
#define Hn 25
#define Gn 100   // 4*H
#define On 64

__device__ __forceinline__ float frcp(float x) { return __builtin_amdgcn_rcpf(x); }

__launch_bounds__(128, 1)
__global__ void lstm_fused(const float* __restrict__ x,
                           const float* __restrict__ W_ih,
                           const float* __restrict__ W_hh,
                           const float* __restrict__ b_ih,
                           const float* __restrict__ b_hh,
                           const float* __restrict__ W_fc,
                           const float* __restrict__ b_fc,
                           float* __restrict__ out) {
    const int b   = blockIdx.x;
    const int tid = threadIdx.x;

    __shared__ float xbuf[2][In];   // double-buffered x[t]
    __shared__ float hbuf[Hn];      // h_{t-1}
    __shared__ float gbuf[Gn];      // activated gates i,f,g,o
    __shared__ float wfc[On * Hn];  // W_fc staged

    // ---- one-time setup ----
    float wih[In];   // per-thread gate row of W_ih
    float whh[Hn];   // per-thread gate row of W_hh
    float bias = 0.f;
    if (tid < Gn) {
        #pragma unroll
        for (int k = 0; k < In; ++k) wih[k] = W_ih[tid * In + k];
        #pragma unroll
        for (int j = 0; j < Hn; ++j) whh[j] = W_hh[tid * Hn + j];
        bias = b_ih[tid] + b_hh[tid];
    }
    for (int idx = tid; idx < On * Hn; idx += 128) wfc[idx] = W_fc[idx];
    const float bfc = (tid < On) ? b_fc[tid] : 0.f;

    if (tid < Hn) hbuf[tid] = 0.f;
    float c = 0.f;

    const float* xrow = x + (size_t)b * Tn * In;
    float*       orow = out + (size_t)b * Tn * On;

    if (tid < In) xbuf[0][tid] = xrow[tid];  // x[0]
    __syncthreads();

    const bool is_tanh_gate = (tid >= 2 * Hn) && (tid < 3 * Hn);

    for (int t = 0; t < Tn; ++t) {
        const int cur = t & 1;
        const int nxt = cur ^ 1;

        // issue prefetch of x[t+1] early; latency overlaps phase A
        float xn = 0.f;
        if (tid < In && (t + 1) < Tn) xn = xrow[(t + 1) * In + tid];

        // ---- phase A: gate pre-activations + activation ----
        float gv = 0.f;
        if (tid < Gn) {
            float a0 = 0.f, a1 = 0.f, a2 = 0.f, a3 = 0.f;
            const float* xb = xbuf[cur];
            #pragma unroll
            for (int k = 0; k < In; k += 4) {
                a0 += wih[k + 0] * xb[k + 0];
                a1 += wih[k + 1] * xb[k + 1];
                a2 += wih[k + 2] * xb[k + 2];
                a3 += wih[k + 3] * xb[k + 3];
            }
            #pragma unroll
            for (int j = 0; j < 24; j += 4) {
                a0 += whh[j + 0] * hbuf[j + 0];
                a1 += whh[j + 1] * hbuf[j + 1];
                a2 += whh[j + 2] * hbuf[j + 2];
                a3 += whh[j + 3] * hbuf[j + 3];
            }
            a0 += whh[24] * hbuf[24];
            float acc = bias + ((a0 + a1) + (a2 + a3));
            // branchless sigmoid/tanh: tanh(a) = 2*sigmoid(2a)-1
            float a2x = is_tanh_gate ? 2.f * acc : acc;
            float s   = frcp(1.f + __expf(-a2x));
            gv = is_tanh_gate ? (2.f * s - 1.f) : s;
        }
        if (tid < In) xbuf[nxt][tid] = xn;     // publish prefetch
        if (tid < Gn) gbuf[tid] = gv;
        __syncthreads();

        // ---- phase B: c/h update (threads 0..24) ----
        if (tid < Hn) {
            const float ig = gbuf[tid];
            const float fg = gbuf[Hn + tid];
            const float gg = gbuf[2 * Hn + tid];
            const float og = gbuf[3 * Hn + tid];
            c = fg * c + ig * gg;
            const float th = 2.f * frcp(1.f + __expf(-2.f * c)) - 1.f;
            hbuf[tid] = og * th;
        }
        __syncthreads();

        // ---- phase C: fused output GEMM (threads 0..63) ----
        if (tid < On) {
            float a0 = bfc, a1 = 0.f, a2 = 0.f, a3 = 0.f;
            const float* wr = &wfc[tid * Hn];
            #pragma unroll
            for (int j = 0; j < 24; j += 4) {
                a0 += wr[j + 0] * hbuf[j + 0];
                a1 += wr[j + 1] * hbuf[j + 1];
                a2 += wr[j + 2] * hbuf[j + 2];
                a3 += wr[j + 3] * hbuf[j + 3];
            }
            a0 += wr[24] * hbuf[24];
            orow[t * On + tid] = (a0 + a1) + (a2 + a3);
        }
        // no barrier needed here: next phase A only reads hbuf/xbuf, which
        // are re-written only after the next __syncthreads()
    }
}

extern "C" void kernel_launch(void* const* d_in, const int* in_sizes, int n_in,
                              void* d_out, int out_size, void* d_ws, size_t ws_size,
                              hipStream_t stream) {
    const float* x    = (const float*)d_in[0];
    const float* W_ih = (const float*)d_in[1];
    const float* W_hh = (const float*)d_in[2];
    const float* b_ih = (const float*)d_in[3];
    const float* b_hh = (const float*)d_in[4];
    const float* W_fc = (const float*)d_in[5];
    const float* b_fc = (const float*)d_in[6];
    float* out = (float*)d_out;

    lstm_fused<<<Bn, 128, 0, stream>>>(x, W_ih, W_hh, b_ih, b_hh, W_fc, b_fc, out);
}

// Round 2
// 900.585 us; speedup vs baseline: 2.3724x; 2.3724x over previous
//
#include <hip/hip_runtime.h>
#include <hip/hip_fp16.h>

// LSTM: B=256, T=1024, I=64, H=25 (4H=100), O=64. fp32 in/out.
// Two kernels:
//  1) gates_gemm: gates_x[b,t,g] = x[b,t,:]·W_ih[g,:] + b_ih[g] + b_hh[g]
//     -> d_ws (fp32 if ws_size allows, else fp16). No time dependence.
//  2) lstm_rec: persistent, 1 block per batch, 192 threads (3 waves):
//     lanes 0..99  : gate dots (25-FMA W_hh row in regs) + activations
//     lanes 100..124: c/h update (c persistent in regs)
//     lanes 128..191: fused output GEMM for step t-1 (overlapped with cell
//                     phase via double-buffered h)

#define Bn 256
#define Tn 1024
#define In 64
#define Hn 25
#define Gn 100
#define On 64

__device__ __forceinline__ float frcp(float x) { return __builtin_amdgcn_rcpf(x); }

// ---------------- kernel 1 ----------------
template <typename ST>
__launch_bounds__(256, 4)
__global__ void gates_gemm(const float* __restrict__ x,
                           const float* __restrict__ W_ih,
                           const float* __restrict__ b_ih,
                           const float* __restrict__ b_hh,
                           ST* __restrict__ gws) {
    const int tid = threadIdx.x;
    const int row = blockIdx.x * 64 + (tid & 63);                 // row = b*Tn + t
    const int q   = __builtin_amdgcn_readfirstlane(tid >> 6);     // wave-uniform
    const int g0  = q * 25;

    // x row (64 floats) into registers, 16B loads
    const float4* xr4 = (const float4*)(x + (size_t)row * In);
    float4 xv[16];
#pragma unroll
    for (int c = 0; c < 16; ++c) xv[c] = xr4[c];

    float acc[25];
#pragma unroll
    for (int j = 0; j < 25; ++j) acc[j] = b_ih[g0 + j] + b_hh[g0 + j];  // scalar loads

    // W_ih rows are wave-uniform -> SMEM (s_load) path, no LDS needed
#pragma unroll
    for (int j = 0; j < 25; ++j) {
        const float4* wr4 = (const float4*)(W_ih + (size_t)(g0 + j) * In);
        float a0 = 0.f, a1 = 0.f, a2 = 0.f, a3 = 0.f;
#pragma unroll
        for (int c = 0; c < 16; ++c) {
            float4 w = wr4[c];
            a0 += w.x * xv[c].x;
            a1 += w.y * xv[c].y;
            a2 += w.z * xv[c].z;
            a3 += w.w * xv[c].w;
        }
        acc[j] += (a0 + a1) + (a2 + a3);
    }

    ST* orow = gws + (size_t)row * Gn + g0;
#pragma unroll
    for (int j = 0; j < 25; ++j) orow[j] = (ST)acc[j];
}

// ---------------- kernel 2 ----------------
template <typename ST>
__launch_bounds__(192, 1)
__global__ void lstm_rec(const ST* __restrict__ gws,
                         const float* __restrict__ W_hh,
                         const float* __restrict__ W_fc,
                         const float* __restrict__ b_fc,
                         float* __restrict__ out) {
    const int b   = blockIdx.x;
    const int tid = threadIdx.x;

    __shared__ float hbuf[2][28];   // padded to 28 for clean b128 reads
    __shared__ float gbuf[104];     // activated gates i,f,g,o

    const bool is_gate = (tid < Gn);
    const bool is_cell = (tid >= 100) && (tid < 125);
    const bool is_out  = (tid >= 128);
    const bool is_tanh = (tid >= 2 * Hn) && (tid < 3 * Hn);

    float whh[25];
    float wfc[25];
    float bfc = 0.f;
    float c   = 0.f;

    if (is_gate) {
#pragma unroll
        for (int j = 0; j < 25; ++j) whh[j] = W_hh[tid * Hn + j];
    }
    if (is_out) {
        const int o = tid - 128;
#pragma unroll
        for (int j = 0; j < 25; ++j) wfc[j] = W_fc[o * Hn + j];
        bfc = b_fc[o];
    }
    if (tid < 28) { hbuf[0][tid] = 0.f; hbuf[1][tid] = 0.f; }

    const ST* gp = gws + (size_t)b * Tn * Gn + tid;   // valid for gate lanes
    float* obase = out + (size_t)b * Tn * On;

    float gx0 = 0.f, gx1 = 0.f;
    if (is_gate) {
        gx0 = (float)gp[0];
        gx1 = (float)gp[Gn];
    }
    __syncthreads();

    for (int t = 0; t < Tn; ++t) {
        // prefetch gates_x[t+2] (address independent of recurrence)
        float gx2 = 0.f;
        if (is_gate && (t + 2) < Tn) gx2 = (float)gp[(size_t)(t + 2) * Gn];

        const float* hp = hbuf[(t + 1) & 1];   // h_{t-1}

        // ---- phase A: gate dots + activation (lanes 0..99) ----
        if (is_gate) {
            float hv[28];
#pragma unroll
            for (int cc = 0; cc < 7; ++cc)
                ((float4*)hv)[cc] = ((const float4*)hp)[cc];   // broadcast b128
            float a0 = gx0, a1 = 0.f, a2 = 0.f, a3 = 0.f;
#pragma unroll
            for (int j = 0; j < 24; j += 4) {
                a0 += whh[j + 0] * hv[j + 0];
                a1 += whh[j + 1] * hv[j + 1];
                a2 += whh[j + 2] * hv[j + 2];
                a3 += whh[j + 3] * hv[j + 3];
            }
            a0 += whh[24] * hv[24];
            float acc = (a0 + a1) + (a2 + a3);
            float aa  = is_tanh ? 2.f * acc : acc;
            float s   = frcp(1.f + __expf(-aa));
            gbuf[tid] = is_tanh ? (2.f * s - 1.f) : s;
        }
        __syncthreads();

        // ---- phase B: c/h update (lanes 100..124) ----
        if (is_cell) {
            const int r = tid - 100;
            const float ig = gbuf[r];
            const float fg = gbuf[r + 25];
            const float gg = gbuf[r + 50];
            const float og = gbuf[r + 75];
            c = fg * c + ig * gg;
            const float th = 2.f * frcp(1.f + __expf(-2.f * c)) - 1.f;
            hbuf[t & 1][r] = og * th;
        }
        // ---- phase C (overlapped with B): output GEMM for step t-1 ----
        if (is_out && t > 0) {
            float hv[28];
#pragma unroll
            for (int cc = 0; cc < 7; ++cc)
                ((float4*)hv)[cc] = ((const float4*)hp)[cc];
            float a0 = bfc, a1 = 0.f, a2 = 0.f, a3 = 0.f;
#pragma unroll
            for (int j = 0; j < 24; j += 4) {
                a0 += wfc[j + 0] * hv[j + 0];
                a1 += wfc[j + 1] * hv[j + 1];
                a2 += wfc[j + 2] * hv[j + 2];
                a3 += wfc[j + 3] * hv[j + 3];
            }
            a0 += wfc[24] * hv[24];
            obase[(size_t)(t - 1) * On + (tid - 128)] = (a0 + a1) + (a2 + a3);
        }
        __syncthreads();

        gx0 = gx1;
        gx1 = gx2;
    }

    // epilogue: output row for t = Tn-1
    if (is_out) {
        const float* hp = hbuf[(Tn - 1) & 1];
        float hv[28];
#pragma unroll
        for (int cc = 0; cc < 7; ++cc)
            ((float4*)hv)[cc] = ((const float4*)hp)[cc];
        float a0 = bfc, a1 = 0.f, a2 = 0.f, a3 = 0.f;
#pragma unroll
        for (int j = 0; j < 24; j += 4) {
            a0 += wfc[j + 0] * hv[j + 0];
            a1 += wfc[j + 1] * hv[j + 1];
            a2 += wfc[j + 2] * hv[j + 2];
            a3 += wfc[j + 3] * hv[j + 3];
        }
        a0 += wfc[24] * hv[24];
        obase[(size_t)(Tn - 1) * On + (tid - 128)] = (a0 + a1) + (a2 + a3);
    }
}

extern "C" void kernel_launch(void* const* d_in, const int* in_sizes, int n_in,
                              void* d_out, int out_size, void* d_ws, size_t ws_size,
                              hipStream_t stream) {
    const float* x    = (const float*)d_in[0];
    const float* W_ih = (const float*)d_in[1];
    const float* W_hh = (const float*)d_in[2];
    const float* b_ih = (const float*)d_in[3];
    const float* b_hh = (const float*)d_in[4];
    const float* W_fc = (const float*)d_in[5];
    const float* b_fc = (const float*)d_in[6];
    float* out = (float*)d_out;

    const size_t need_f32 = (size_t)Bn * Tn * Gn * sizeof(float);   // 104.9 MB
    const int nrow_blocks = (Bn * Tn) / 64;                         // 4096

    if (ws_size >= need_f32) {
        float* gws = (float*)d_ws;
        gates_gemm<float><<<nrow_blocks, 256, 0, stream>>>(x, W_ih, b_ih, b_hh, gws);
        lstm_rec<float><<<Bn, 192, 0, stream>>>(gws, W_hh, W_fc, b_fc, out);
    } else {
        __half* gws = (__half*)d_ws;
        gates_gemm<__half><<<nrow_blocks, 256, 0, stream>>>(x, W_ih, b_ih, b_hh, gws);
        lstm_rec<__half><<<Bn, 192, 0, stream>>>(gws, W_hh, W_fc, b_fc, out);
    }
}

// Round 3
// 626.280 us; speedup vs baseline: 3.4115x; 1.4380x over previous
//
#include <hip/hip_runtime.h>
#include <hip/hip_fp16.h>

// LSTM: B=256, T=1024, I=64, H=25 (4H=100), O=64. fp32 in/out.
//
// k1 gates_gemm_t: gates_x = x·W_ihᵀ + b_ih + b_hh, stored GATE-MAJOR
//   gws[g][b*T+t] (g in [0,100)) so all stores are coalesced 128-B wave
//   stores (round-2's row-major scattered 2-B stores cost ~200 µs).
//
// k2 lstm_rec2: one wave per batch element, ZERO LDS, ZERO barriers.
//   Lane r<25 owns hidden unit r: computes i_r,f_r,g_r,o_r (100 FMAs) and
//   the cell update in-lane; h broadcast to all lanes via v_readlane into
//   SGPRs (VALU latency, not a 120-cyc LDS round trip). All 64 lanes do
//   the fused FC output for h_{t-1} (hides activation latency).

#define Bn 256
#define Tn 1024
#define In 64
#define Hn 25
#define Gn 100
#define On 64
#define BT (Bn * Tn)

__device__ __forceinline__ float frcp(float x) { return __builtin_amdgcn_rcpf(x); }
__device__ __forceinline__ float sigm(float x) { return frcp(1.f + __expf(-x)); }
__device__ __forceinline__ float bcast(float v, int lane) {
    return __int_as_float(__builtin_amdgcn_readlane(__float_as_int(v), lane));
}

// ---------------- kernel 1: input GEMM, gate-major output ----------------
template <typename ST>
__launch_bounds__(256, 2)
__global__ void gates_gemm_t(const float* __restrict__ x,
                             const float* __restrict__ W_ih,
                             const float* __restrict__ b_ih,
                             const float* __restrict__ b_hh,
                             ST* __restrict__ gws) {
    const int tid = threadIdx.x;
    const int l   = tid & 63;
    const int q   = __builtin_amdgcn_readfirstlane(tid >> 6);  // gate type 0..3
    const int row = blockIdx.x * 64 + l;                        // b*T + t
    const int g0  = q * Hn;

    // x row (64 floats) into registers
    const float4* xr = (const float4*)(x + (size_t)row * In);
    float4 xv[16];
#pragma unroll
    for (int c = 0; c < 16; ++c) xv[c] = xr[c];

#pragma unroll
    for (int j = 0; j < Hn; ++j) {
        const int g = g0 + j;
        const float4* wr = (const float4*)(W_ih + (size_t)g * In);  // wave-uniform
        float a0 = 0.f, a1 = 0.f, a2 = 0.f, a3 = 0.f;
#pragma unroll
        for (int c = 0; c < 16; ++c) {
            float4 w = wr[c];
            a0 += w.x * xv[c].x;
            a1 += w.y * xv[c].y;
            a2 += w.z * xv[c].z;
            a3 += w.w * xv[c].w;
        }
        float acc = (a0 + a1) + (a2 + a3) + b_ih[g] + b_hh[g];
        gws[(size_t)g * BT + row] = (ST)acc;   // coalesced: lanes -> consecutive rows
    }
}

// ---------------- kernel 2: recurrence, 1 wave / batch ----------------
template <typename ST>
__launch_bounds__(64, 1)
__global__ void lstm_rec2(const ST* __restrict__ gws,
                          const float* __restrict__ W_hh,
                          const float* __restrict__ W_fc,
                          const float* __restrict__ b_fc,
                          float* __restrict__ out) {
    const int b  = blockIdx.x;
    const int r  = threadIdx.x;              // 0..63
    const int rr = (r < Hn) ? r : (Hn - 1);  // clamp: lanes >=25 compute garbage gates, never used

    // per-lane weights: rows of W_hh for this unit's 4 gates + W_fc row
    float wi[Hn], wf[Hn], wg[Hn], wo[Hn], wv[Hn];
#pragma unroll
    for (int j = 0; j < Hn; ++j) {
        wi[j] = W_hh[(0 * Hn + rr) * Hn + j];
        wf[j] = W_hh[(1 * Hn + rr) * Hn + j];
        wg[j] = W_hh[(2 * Hn + rr) * Hn + j];
        wo[j] = W_hh[(3 * Hn + rr) * Hn + j];
        wv[j] = W_fc[r * Hn + j];
    }
    const float bfc = b_fc[r];

    const ST* gi = gws + (size_t)(0 * Hn + rr) * BT + (size_t)b * Tn;
    const ST* gf = gws + (size_t)(1 * Hn + rr) * BT + (size_t)b * Tn;
    const ST* gg = gws + (size_t)(2 * Hn + rr) * BT + (size_t)b * Tn;
    const ST* go = gws + (size_t)(3 * Hn + rr) * BT + (size_t)b * Tn;
    float* op = out + (size_t)b * Tn * On + r;

    // depth-3 register prefetch queues for gates_x
    ST qi0 = gi[0], qf0 = gf[0], qg0 = gg[0], qo0 = go[0];
    ST qi1 = gi[1], qf1 = gf[1], qg1 = gg[1], qo1 = go[1];
    ST qi2 = gi[2], qf2 = gf[2], qg2 = gg[2], qo2 = go[2];

    float hb[Hn];   // broadcast h_{t-1}: uniform values (SGPRs)
#pragma unroll
    for (int j = 0; j < Hn; ++j) hb[j] = 0.f;
    float c = 0.f;

    for (int t = 0; t < Tn; ++t) {
        const int tp = (t + 3 < Tn) ? (t + 3) : (Tn - 1);
        ST ni = gi[tp], nf = gf[tp], ng = gg[tp], no = go[tp];  // prefetch

        // gate pre-activations (lane r = unit r; 4 independent FMA chains)
        float ai = (float)qi0, af = (float)qf0, ag = (float)qg0, ao = (float)qo0;
#pragma unroll
        for (int j = 0; j < Hn; ++j) {
            ai += wi[j] * hb[j];
            af += wf[j] * hb[j];
            ag += wg[j] * hb[j];
            ao += wo[j] * hb[j];
        }

        // fused FC output for h_{t-1} (independent of this step's chain;
        // its issue hides the activation latency below)
        if (t > 0) {
            float a0 = bfc, a1 = 0.f;
#pragma unroll
            for (int j = 0; j < 24; j += 2) {
                a0 += wv[j + 0] * hb[j + 0];
                a1 += wv[j + 1] * hb[j + 1];
            }
            a0 += wv[24] * hb[24];
            op[(size_t)(t - 1) * On] = a0 + a1;
        }

        // activations + cell update, all in-lane
        const float I  = sigm(ai);
        const float F  = sigm(af);
        const float G  = 2.f * sigm(2.f * ag) - 1.f;   // tanh
        const float O_ = sigm(ao);
        c = F * c + I * G;
        const float th = 2.f * sigm(2.f * c) - 1.f;    // tanh(c)
        const float h  = O_ * th;

        // broadcast h to all lanes via readlane -> SGPRs
#pragma unroll
        for (int j = 0; j < Hn; ++j) hb[j] = bcast(h, j);

        // rotate prefetch queues
        qi0 = qi1; qi1 = qi2; qi2 = ni;
        qf0 = qf1; qf1 = qf2; qf2 = nf;
        qg0 = qg1; qg1 = qg2; qg2 = ng;
        qo0 = qo1; qo1 = qo2; qo2 = no;
    }

    // final FC row (h_{T-1})
    {
        float a0 = bfc, a1 = 0.f;
#pragma unroll
        for (int j = 0; j < 24; j += 2) {
            a0 += wv[j + 0] * hb[j + 0];
            a1 += wv[j + 1] * hb[j + 1];
        }
        a0 += wv[24] * hb[24];
        op[(size_t)(Tn - 1) * On] = a0 + a1;
    }
}

extern "C" void kernel_launch(void* const* d_in, const int* in_sizes, int n_in,
                              void* d_out, int out_size, void* d_ws, size_t ws_size,
                              hipStream_t stream) {
    const float* x    = (const float*)d_in[0];
    const float* W_ih = (const float*)d_in[1];
    const float* W_hh = (const float*)d_in[2];
    const float* b_ih = (const float*)d_in[3];
    const float* b_hh = (const float*)d_in[4];
    const float* W_fc = (const float*)d_in[5];
    const float* b_fc = (const float*)d_in[6];
    float* out = (float*)d_out;

    const size_t need_f32 = (size_t)Gn * BT * sizeof(float);   // 104.9 MB
    const int nb = BT / 64;                                    // 4096 blocks

    if (ws_size >= need_f32) {
        float* gws = (float*)d_ws;
        gates_gemm_t<float><<<nb, 256, 0, stream>>>(x, W_ih, b_ih, b_hh, gws);
        lstm_rec2<float><<<Bn, 64, 0, stream>>>(gws, W_hh, W_fc, b_fc, out);
    } else {
        __half* gws = (__half*)d_ws;
        gates_gemm_t<__half><<<nb, 256, 0, stream>>>(x, W_ih, b_ih, b_hh, gws);
        lstm_rec2<__half><<<Bn, 64, 0, stream>>>(gws, W_hh, W_fc, b_fc, out);
    }
}